// Round 5
// baseline (3091.143 us; speedup 1.0000x reference)
//
#include <hip/hip_runtime.h>
#include <stdint.h>

#define NPTS 8192
#define NS   2048
#define KNNK 32

typedef unsigned long long u64;
typedef float f32x2 __attribute__((ext_vector_type(2)));

// DPP-based 64-lane reduces. CDNA keeps gfx9 DPP ctrls:
// quad_perm xor1=0xB1, xor2=0x4E, ROW_HALF_MIRROR=0x141 (lane^7),
// ROW_MIRROR=0x140 (lane^15), ROW_BCAST15=0x142, ROW_BCAST31=0x143.
// After the 6 steps lanes 48..63 hold the full 64-lane result; readlane 63.
__device__ __forceinline__ float wave_max_f32_dpp(float x) {
    int t;
    t = __builtin_amdgcn_update_dpp(0, __float_as_int(x), 0xB1, 0xF, 0xF, false);
    x = fmaxf(x, __int_as_float(t));
    t = __builtin_amdgcn_update_dpp(0, __float_as_int(x), 0x4E, 0xF, 0xF, false);
    x = fmaxf(x, __int_as_float(t));
    t = __builtin_amdgcn_update_dpp(0, __float_as_int(x), 0x141, 0xF, 0xF, false);
    x = fmaxf(x, __int_as_float(t));
    t = __builtin_amdgcn_update_dpp(0, __float_as_int(x), 0x140, 0xF, 0xF, false);
    x = fmaxf(x, __int_as_float(t));
    // bcast steps: non-written lanes keep old=0; d2>=0 so max(x,0)=x is a no-op
    t = __builtin_amdgcn_update_dpp(0, __float_as_int(x), 0x142, 0xF, 0xF, false);
    x = fmaxf(x, __int_as_float(t));
    t = __builtin_amdgcn_update_dpp(0, __float_as_int(x), 0x143, 0xF, 0xF, false);
    x = fmaxf(x, __int_as_float(t));
    return x;
}

__device__ __forceinline__ int wave_min_i32_dpp(int x) {
    const int INF = 0x7FFFFFFF;
    int t;
    t = __builtin_amdgcn_update_dpp(INF, x, 0xB1, 0xF, 0xF, false);
    x = t < x ? t : x;
    t = __builtin_amdgcn_update_dpp(INF, x, 0x4E, 0xF, 0xF, false);
    x = t < x ? t : x;
    t = __builtin_amdgcn_update_dpp(INF, x, 0x141, 0xF, 0xF, false);
    x = t < x ? t : x;
    t = __builtin_amdgcn_update_dpp(INF, x, 0x140, 0xF, 0xF, false);
    x = t < x ? t : x;
    t = __builtin_amdgcn_update_dpp(INF, x, 0x142, 0xF, 0xF, false);
    x = t < x ? t : x;
    t = __builtin_amdgcn_update_dpp(INF, x, 0x143, 0xF, 0xF, false);
    x = t < x ? t : x;
    return x;
}

// ============================ FPS =============================
// One block per (b,t) frame, 512 threads (8 waves), 16 points/thread as
// 8 f32x2 (packed v_pk_* math; contract(off) keeps rn mul/add bit-exact,
// sum order ((x+y)+z)). ONE barrier per iteration, NO atomics:
// each wave's lane0 plain-writes its reduced key to wkey[i&1][wave];
// after the barrier all threads tree-max the 8 slots (broadcast reads).
// Parity double-buffer is WAR-safe: same-parity reuse is 2 barriers away.
// key = (d2bits<<32)|(8191-idx): argmax with lowest-index tie-break
// (d2>=0 so f32 bits are order-monotone; matches jnp.argmax semantics).
__global__ __launch_bounds__(512)
void fps_kernel(const float* __restrict__ pts,
                float* __restrict__ out_xyz)
{
#pragma clang fp contract(off)
    const int bt  = blockIdx.x;        // b*4 + t0
    const int tid = threadIdx.x;
    const float* frame = pts + (size_t)bt * NPTS * 6;

    __shared__ float4 p4[NPTS];        // 128 KB coords copy
    __shared__ u64 wkey[2][8];

    f32x2 x2[8], y2[8], z2[8], dd2[8];
#pragma unroll
    for (int j = 0; j < 16; ++j) {
        int n = j * 512 + tid;
        float x = frame[n*6+0], y = frame[n*6+1], z = frame[n*6+2];
        x2[j >> 1][j & 1] = x;
        y2[j >> 1][j & 1] = y;
        z2[j >> 1][j & 1] = z;
        dd2[j >> 1][j & 1] = 3.4028234663852886e38f;
        p4[n] = make_float4(x, y, z, 0.0f);
    }
    if (tid == 0) {                    // selection 0 = point 0
        float* ow = out_xyz + (size_t)bt * NS * 3;
        ow[0] = x2[0][0]; ow[1] = y2[0][0]; ow[2] = z2[0][0];
    }
    __syncthreads();
    float sx = p4[0].x, sy = p4[0].y, sz = p4[0].z;

    for (int i = 1; i < NS; ++i) {
        // packed update vs previous selection, track local max
        f32x2 sxv = {sx, sx}, syv = {sy, sy}, szv = {sz, sz};
        f32x2 m2 = {0.0f, 0.0f};
#pragma unroll
        for (int q = 0; q < 8; ++q) {
            f32x2 dx = x2[q] - sxv;
            f32x2 dy = y2[q] - syv;
            f32x2 dz = z2[q] - szv;
            f32x2 dd = (dx*dx + dy*dy) + dz*dz;
            f32x2 nd;
            nd[0] = fminf(dd2[q][0], dd[0]);
            nd[1] = fminf(dd2[q][1], dd[1]);
            dd2[q] = nd;
            m2[0] = fmaxf(m2[0], nd[0]);
            m2[1] = fmaxf(m2[1], nd[1]);
        }
        float mloc = fmaxf(m2[0], m2[1]);
        // lowest local slot holding mloc: independent cmps -> mask -> ctz
        unsigned mask = 0;
#pragma unroll
        for (int j = 0; j < 16; ++j)
            mask |= (dd2[j >> 1][j & 1] == mloc) ? (1u << j) : 0u;
        int bestn = __builtin_ctz(mask) * 512 + tid;
        // wave reduce: max value, then min index among value-ties
        float wM = wave_max_f32_dpp(mloc);
        float M = __int_as_float(__builtin_amdgcn_readlane(__float_as_int(wM), 63));
        int cand = (mloc == M) ? bestn : 0x7FFFFFFF;
        int wI = wave_min_i32_dpp(cand);
        int idxm = __builtin_amdgcn_readlane(wI, 63);
        if ((tid & 63) == 0)
            wkey[i & 1][tid >> 6] =
                ((u64)__float_as_uint(M) << 32) | (unsigned)(8191 - idxm);
        __syncthreads();
        // tree-max of the 8 wave keys (broadcast reads, no atomics)
        const u64* wk = wkey[i & 1];
        u64 a0 = wk[0] > wk[1] ? wk[0] : wk[1];
        u64 a1 = wk[2] > wk[3] ? wk[2] : wk[3];
        u64 a2 = wk[4] > wk[5] ? wk[4] : wk[5];
        u64 a3 = wk[6] > wk[7] ? wk[6] : wk[7];
        u64 b0 = a0 > a1 ? a0 : a1;
        u64 b1 = a2 > a3 ? a2 : a3;
        u64 k  = b0 > b1 ? b0 : b1;
        int idx = 8191 - (int)(k & 0xFFFFFFFFu);
        float4 c = p4[idx];            // broadcast ds_read_b128
        sx = c.x; sy = c.y; sz = c.z;
        if (tid == 0) {
            float* ow = out_xyz + ((size_t)bt * NS + i) * 3;
            ow[0] = sx; ow[1] = sy; ow[2] = sz;
        }
    }
}

// ============================ KNN =============================
// (unchanged from R4 — rewrite deferred for clean attribution)
__device__ __forceinline__ void knn_compact(u64* st, int lane, int& cnt, u64& rk)
{
    for (int e = 0; e < 32; ++e)
        if (e >= cnt) st[(e + 32) * 64 + lane] = ~0ull;
    for (int k = 2; k <= 32; k <<= 1)
        for (int j = k >> 1; j > 0; j >>= 1)
            for (int i = 0; i < 32; ++i) {
                int l = i ^ j;
                if (l > i) {
                    u64 a = st[(i + 32) * 64 + lane];
                    u64 b = st[(l + 32) * 64 + lane];
                    bool asc = ((i & k) == 0);
                    if ((a > b) == asc) {
                        st[(i + 32) * 64 + lane] = b;
                        st[(l + 32) * 64 + lane] = a;
                    }
                }
            }
    for (int i = 0; i < 32; ++i) {
        u64 a = st[i * 64 + lane];
        u64 b = st[(63 - i) * 64 + lane];
        if (b < a) st[i * 64 + lane] = b;
    }
    for (int j = 16; j > 0; j >>= 1)
        for (int i = 0; i < 32; ++i) {
            int l = i ^ j;
            if (l > i) {
                u64 a = st[i * 64 + lane];
                u64 b = st[l * 64 + lane];
                if (a > b) {
                    st[i * 64 + lane] = b;
                    st[l * 64 + lane] = a;
                }
            }
        }
    rk = st[31 * 64 + lane];
    cnt = 0;
}

__global__ __launch_bounds__(64)
void knn_kernel(const float* __restrict__ pts,
                const float* __restrict__ anchors,
                unsigned short* __restrict__ knn_out)
{
    const int blk  = blockIdx.x;       // 8bt * 3di * 32 sblk
    const int bt   = blk / 96;
    const int r    = blk % 96;
    const int di   = r / 32;
    const int sblk = r % 32;
    const int b = bt >> 2, t0 = bt & 3;
    int lnb = t0 + di - 1; lnb = lnb < 0 ? 0 : (lnb > 3 ? 3 : lnb);
    const float* nb = pts + (size_t)(b * 4 + lnb) * NPTS * 6;
    const int lane = threadIdx.x;
    const int s    = sblk * 64 + lane;

    const float* ap = anchors + ((size_t)bt * NS + s) * 3;
    float ax = ap[0], ay = ap[1], az = ap[2];

    __shared__ u64 st[65 * 64];        // 33.25 KB
    __shared__ float4 tile[512];       // 8 KB

    for (int e = 0; e < 64; ++e) st[e * 64 + lane] = ~0ull;
    u64 rk = ~0ull;
    int cnt = 0;

    for (int tb = 0; tb < NPTS; tb += 512) {
        __syncthreads();
#pragma unroll
        for (int q = 0; q < 8; ++q) {
            int c = q * 64 + lane;
            int n = tb + c;
            tile[c] = make_float4(nb[n*6+0], nb[n*6+1], nb[n*6+2], 0.0f);
        }
        __syncthreads();
        for (int c0 = 0; c0 < 512; c0 += 8) {
#pragma unroll
            for (int j = 0; j < 8; ++j) {
                float4 qv = tile[c0 + j];
                float dx = __fsub_rn(ax, qv.x);
                float dy = __fsub_rn(ay, qv.y);
                float dz = __fsub_rn(az, qv.z);
                float d2 = __fadd_rn(__fadd_rn(__fmul_rn(dx,dx), __fmul_rn(dy,dy)),
                                     __fmul_rn(dz,dz));
                u64 key = ((u64)__float_as_uint(d2) << 32)
                        | (unsigned)(tb + c0 + j);
                bool p = key < rk;
                int row = p ? (32 + cnt) : 64;
                st[row * 64 + lane] = key;
                cnt += p ? 1 : 0;
            }
            if (__any(cnt >= 24)) knn_compact(st, lane, cnt, rk);
        }
    }
    knn_compact(st, lane, cnt, rk);

    unsigned short* op = knn_out + (((size_t)bt * 3 + di) * NS + s) * KNNK;
#pragma unroll
    for (int e = 0; e < 32; ++e)
        op[e] = (unsigned short)(st[e * 64 + lane] & 0xFFFFull);
}

// ============================ MLP =============================
// Block = 2 anchors x 128 channels. Phase-2 register-tiled: each thread
// owns a 4p x 8k tile (acc[4][8]); per o: 1 b128 WmT read (contiguous per
// lane) + 2 b128 h1 broadcast reads vs 32 FMAs -> VALU-bound, LDS /2.6.
// h1 stride 32: bank-clean for phase-1 column writes AND phase-2
// broadcast reads. Cross-kt max via small pmax LDS pass.
__global__ __launch_bounds__(256)
void mlp_kernel(const float* __restrict__ pts,
                const float* __restrict__ anchors,
                const unsigned short* __restrict__ knn,
                const float* __restrict__ Wd,
                const float* __restrict__ Wm,
                float* __restrict__ out_feats)
{
    const int blk   = blockIdx.x;
    const int bt    = blk >> 10;
    const int spair = blk & 1023;
    const int b = bt >> 2, t0 = bt & 3;
    const int tid = threadIdx.x;
    const int a   = tid >> 7;      // local anchor (tile AND output)
    const int r   = tid & 127;
    const int pt  = r & 31;        // tile p-group: p0 = pt*4
    const int kt  = r >> 5;        // tile k-group: k0 = kt*8
    const int p   = r;             // output channel for reduce/store
    const int s   = spair * 2 + a;
    const int p0  = pt * 4, k0 = kt * 8;

    __shared__ float WmT[64 * 128];      // 32 KB, [o][p]
    __shared__ float Wds[256];           // [o][c]
    __shared__ float h1[2][64][32];      // 16 KB, stride 32
    __shared__ float d4s[2][32][4];
    __shared__ float pmax[2][4][128];    // [a][kt][p]

    for (int i = tid; i < 8192; i += 256) {
        int pp = i >> 6, oo = i & 63;
        WmT[oo * 128 + pp] = Wm[i];
    }
    Wds[tid & 255] = Wd[tid & 255];

    float fsum = 0.0f;

    for (int dd = 0; dd < 3; ++dd) {
        __syncthreads();   // protect d4s/h1/pmax reuse (and WmT/Wds on dd=0)
        if (tid < 64) {
            int sa = tid >> 5, k = tid & 31;
            int ss = spair * 2 + sa;
            int lnb = t0 + dd - 1; lnb = lnb < 0 ? 0 : (lnb > 3 ? 3 : lnb);
            const float* nbf = pts + (size_t)(b*4 + lnb) * NPTS * 6;
            const float* ap = anchors + ((size_t)bt * NS + ss) * 3;
            int idx = knn[(((size_t)bt*3 + dd) * NS + ss) * KNNK + k];
            d4s[sa][k][0] = nbf[idx*6+0] - ap[0];
            d4s[sa][k][1] = nbf[idx*6+1] - ap[1];
            d4s[sa][k][2] = nbf[idx*6+2] - ap[2];
            d4s[sa][k][3] = (float)(dd - 1);
        }
        __syncthreads();
        // phase 1: h1[a][o][k], 128 threads/anchor = (k 0..31) x (oq 0..3)
        {
            int k  = tid & 31;
            int oq = (tid >> 5) & 3;
            float4 dv = *(const float4*)&d4s[a][k][0];
#pragma unroll
            for (int ii = 0; ii < 16; ++ii) {
                int o = oq * 16 + ii;
                float4 w = *(const float4*)&Wds[o * 4];
                float h = fmaf(dv.x, w.x, fmaf(dv.y, w.y, fmaf(dv.z, w.z, dv.w * w.w)));
                h1[a][o][k] = fmaxf(h, 0.0f);
            }
        }
        __syncthreads();
        // phase 2: 4p x 8k register tile
        float acc[4][8];
#pragma unroll
        for (int i = 0; i < 4; ++i)
#pragma unroll
            for (int j = 0; j < 8; ++j) acc[i][j] = 0.0f;
        for (int o = 0; o < 64; ++o) {
            float4 wv = *(const float4*)&WmT[o * 128 + p0];
            float4 h0 = *(const float4*)&h1[a][o][k0];
            float4 h4 = *(const float4*)&h1[a][o][k0 + 4];
#pragma unroll
            for (int i = 0; i < 4; ++i) {
                float w = (i == 0) ? wv.x : (i == 1) ? wv.y : (i == 2) ? wv.z : wv.w;
                acc[i][0] = fmaf(w, h0.x, acc[i][0]);
                acc[i][1] = fmaf(w, h0.y, acc[i][1]);
                acc[i][2] = fmaf(w, h0.z, acc[i][2]);
                acc[i][3] = fmaf(w, h0.w, acc[i][3]);
                acc[i][4] = fmaf(w, h4.x, acc[i][4]);
                acc[i][5] = fmaf(w, h4.y, acc[i][5]);
                acc[i][6] = fmaf(w, h4.z, acc[i][6]);
                acc[i][7] = fmaf(w, h4.w, acc[i][7]);
            }
        }
        // per-p max over this thread's 8 k's
        float4 pm;
#pragma unroll
        for (int i = 0; i < 4; ++i) {
            float m = acc[i][0];
#pragma unroll
            for (int j = 1; j < 8; ++j) m = fmaxf(m, acc[i][j]);
            ((float*)&pm)[i] = m;
        }
        *(float4*)&pmax[a][kt][p0] = pm;
        __syncthreads();
        // final: thread (a,p) maxes the 4 kt partials
        float m = fmaxf(fmaxf(pmax[a][0][p], pmax[a][1][p]),
                        fmaxf(pmax[a][2][p], pmax[a][3][p]));
        fsum += fmaxf(m, 0.0f);   // max_k relu(x) == relu(max_k x)
    }
    out_feats[((size_t)bt * 128 + p) * NS + s] = fsum;
}

// ========================== launcher ==========================
extern "C" void kernel_launch(void* const* d_in, const int* in_sizes, int n_in,
                              void* d_out, int out_size, void* d_ws, size_t ws_size,
                              hipStream_t stream)
{
    const float* pts = (const float*)d_in[0];   // [2,4,8192,6]
    const float* Wd  = (const float*)d_in[1];   // [64,4]
    const float* Wm  = (const float*)d_in[2];   // [128,64]

    float* out_xyz   = (float*)d_out;                 // [2,4,2048,3] == anchors
    float* out_feats = out_xyz + 8 * NS * 3;          // [2,4,128,2048]

    unsigned short* knn = (unsigned short*)d_ws;      // 8*3*2048*32 u16

    fps_kernel<<<8, 512, 0, stream>>>(pts, out_xyz);
    knn_kernel<<<8 * 3 * 32, 64, 0, stream>>>(pts, out_xyz, knn);
    mlp_kernel<<<8 * (NS / 2), 256, 0, stream>>>(pts, out_xyz, knn, Wd, Wm, out_feats);
}

// Round 6
// 3086.903 us; speedup vs baseline: 1.0014x; 1.0014x over previous
//
#include <hip/hip_runtime.h>
#include <stdint.h>

#define NPTS 8192
#define NS   2048
#define KNNK 32

typedef unsigned long long u64;
typedef float f32x2 __attribute__((ext_vector_type(2)));

// DPP-based 64-lane reduces. CDNA keeps gfx9 DPP ctrls:
// quad_perm xor1=0xB1, xor2=0x4E, ROW_HALF_MIRROR=0x141, ROW_MIRROR=0x140,
// ROW_BCAST15=0x142, ROW_BCAST31=0x143.
// After the 6 steps lanes 48..63 hold the full 64-lane result (lane 63 used).
__device__ __forceinline__ float wave_max_f32_dpp(float x) {
    int t;
    t = __builtin_amdgcn_update_dpp(0, __float_as_int(x), 0xB1, 0xF, 0xF, false);
    x = fmaxf(x, __int_as_float(t));
    t = __builtin_amdgcn_update_dpp(0, __float_as_int(x), 0x4E, 0xF, 0xF, false);
    x = fmaxf(x, __int_as_float(t));
    t = __builtin_amdgcn_update_dpp(0, __float_as_int(x), 0x141, 0xF, 0xF, false);
    x = fmaxf(x, __int_as_float(t));
    t = __builtin_amdgcn_update_dpp(0, __float_as_int(x), 0x140, 0xF, 0xF, false);
    x = fmaxf(x, __int_as_float(t));
    // non-written lanes keep old=0; d2>=0 so max(x,0)=x is a no-op
    t = __builtin_amdgcn_update_dpp(0, __float_as_int(x), 0x142, 0xF, 0xF, false);
    x = fmaxf(x, __int_as_float(t));
    t = __builtin_amdgcn_update_dpp(0, __float_as_int(x), 0x143, 0xF, 0xF, false);
    x = fmaxf(x, __int_as_float(t));
    return x;
}

__device__ __forceinline__ int wave_min_i32_dpp(int x) {
    const int INF = 0x7FFFFFFF;
    int t;
    t = __builtin_amdgcn_update_dpp(INF, x, 0xB1, 0xF, 0xF, false);
    x = t < x ? t : x;
    t = __builtin_amdgcn_update_dpp(INF, x, 0x4E, 0xF, 0xF, false);
    x = t < x ? t : x;
    t = __builtin_amdgcn_update_dpp(INF, x, 0x141, 0xF, 0xF, false);
    x = t < x ? t : x;
    t = __builtin_amdgcn_update_dpp(INF, x, 0x140, 0xF, 0xF, false);
    x = t < x ? t : x;
    t = __builtin_amdgcn_update_dpp(INF, x, 0x142, 0xF, 0xF, false);
    x = t < x ? t : x;
    t = __builtin_amdgcn_update_dpp(INF, x, 0x143, 0xF, 0xF, false);
    x = t < x ? t : x;
    return x;
}

// ============================ FPS =============================
// One block per (b,t) frame, 512 threads (8 waves), 16 points/thread as
// 8 f32x2 (packed math; contract(off) keeps rn mul/add bit-exact, sum
// order ((x+y)+z)). VALU-issue-bound -> minimal always-path:
//   update + pk min/max -> mloc; f32 DPP wave-max; lane63 -> wmaxs[w];
//   barrier A; all: 8-float tree-max -> M;
//   index scan + i32 DPP-min + u32 atomicMin(selIdx[pi]) ONLY in waves
//   where some lane has mloc==M (7/8 waves s_cbranch past it);
//   barrier B; coords from p4[selIdx[pi]]; tid0 resets selIdx[pi^1].
// Exact argmax w/ lowest-index tie-break (min global idx over d==M).
// selIdx parity: write(i,post-A) / read(i,post-B) / reset other slot
// (i,post-B) / next write (i+1,post-A(i+1)) -- each pair barrier-separated.
__global__ __launch_bounds__(512)
void fps_kernel(const float* __restrict__ pts,
                float* __restrict__ out_xyz)
{
#pragma clang fp contract(off)
    const int bt  = blockIdx.x;        // b*4 + t0
    const int tid = threadIdx.x;
    const float* frame = pts + (size_t)bt * NPTS * 6;

    __shared__ float4 p4[NPTS];        // 128 KB coords copy
    __shared__ float wmaxs[8];
    __shared__ unsigned selIdx[2];

    f32x2 x2[8], y2[8], z2[8], dd2[8];
#pragma unroll
    for (int j = 0; j < 16; ++j) {
        int n = j * 512 + tid;
        float x = frame[n*6+0], y = frame[n*6+1], z = frame[n*6+2];
        x2[j >> 1][j & 1] = x;
        y2[j >> 1][j & 1] = y;
        z2[j >> 1][j & 1] = z;
        dd2[j >> 1][j & 1] = 3.4028234663852886e38f;
        p4[n] = make_float4(x, y, z, 0.0f);
    }
    if (tid < 2) selIdx[tid] = 0x7FFFFFFFu;
    if (tid == 0) {                    // selection 0 = point 0
        float* ow = out_xyz + (size_t)bt * NS * 3;
        ow[0] = x2[0][0]; ow[1] = y2[0][0]; ow[2] = z2[0][0];
    }
    __syncthreads();
    float sx = p4[0].x, sy = p4[0].y, sz = p4[0].z;

    for (int i = 1; i < NS; ++i) {
        const int pi = i & 1;
        // packed update vs previous selection, packed min/max accumulate
        f32x2 sxv = {sx, sx}, syv = {sy, sy}, szv = {sz, sz};
        f32x2 m2 = {0.0f, 0.0f};
#pragma unroll
        for (int q = 0; q < 8; ++q) {
            f32x2 dx = x2[q] - sxv;
            f32x2 dy = y2[q] - syv;
            f32x2 dz = z2[q] - szv;
            f32x2 dd = (dx*dx + dy*dy) + dz*dz;
            f32x2 nd;
            nd[0] = fminf(dd2[q][0], dd[0]);
            nd[1] = fminf(dd2[q][1], dd[1]);
            dd2[q] = nd;
            m2[0] = fmaxf(m2[0], nd[0]);
            m2[1] = fmaxf(m2[1], nd[1]);
        }
        float mloc = fmaxf(m2[0], m2[1]);
        // wave max (f32); lane 63 holds the full-wave result
        float wM = wave_max_f32_dpp(mloc);
        if ((tid & 63) == 63) wmaxs[tid >> 6] = wM;
        __syncthreads();               // A: wmaxs visible
        float4 w0 = *(const float4*)&wmaxs[0];
        float4 w1 = *(const float4*)&wmaxs[4];
        float M = fmaxf(fmaxf(fmaxf(w0.x, w0.y), fmaxf(w0.z, w0.w)),
                        fmaxf(fmaxf(w1.x, w1.y), fmaxf(w1.z, w1.w)));
        // only the wave(s) containing the global max do the index work
        bool match = (mloc == M);
        if (__any(match)) {
            unsigned mask = 0;
#pragma unroll
            for (int j = 0; j < 16; ++j)
                mask |= (dd2[j >> 1][j & 1] == M) ? (1u << j) : 0u;
            int bestn = mask ? (int)(__builtin_ctz(mask) * 512 + tid)
                             : 0x7FFFFFFF;
            int wI = wave_min_i32_dpp(bestn);
            if ((tid & 63) == 63) atomicMin(&selIdx[pi], (unsigned)wI);
        }
        __syncthreads();               // B: selIdx final
        unsigned idx = selIdx[pi];
        if (tid == 0) selIdx[pi ^ 1] = 0x7FFFFFFFu;  // for iter i+1
        float4 c = p4[idx];            // broadcast ds_read_b128
        sx = c.x; sy = c.y; sz = c.z;
        if (tid == 0) {
            float* ow = out_xyz + ((size_t)bt * NS + i) * 3;
            ow[0] = sx; ow[1] = sy; ow[2] = sz;
        }
    }
}

// ============================ KNN =============================
// (unchanged — next round's target, kept for clean attribution)
__device__ __forceinline__ void knn_compact(u64* st, int lane, int& cnt, u64& rk)
{
    for (int e = 0; e < 32; ++e)
        if (e >= cnt) st[(e + 32) * 64 + lane] = ~0ull;
    for (int k = 2; k <= 32; k <<= 1)
        for (int j = k >> 1; j > 0; j >>= 1)
            for (int i = 0; i < 32; ++i) {
                int l = i ^ j;
                if (l > i) {
                    u64 a = st[(i + 32) * 64 + lane];
                    u64 b = st[(l + 32) * 64 + lane];
                    bool asc = ((i & k) == 0);
                    if ((a > b) == asc) {
                        st[(i + 32) * 64 + lane] = b;
                        st[(l + 32) * 64 + lane] = a;
                    }
                }
            }
    for (int i = 0; i < 32; ++i) {
        u64 a = st[i * 64 + lane];
        u64 b = st[(63 - i) * 64 + lane];
        if (b < a) st[i * 64 + lane] = b;
    }
    for (int j = 16; j > 0; j >>= 1)
        for (int i = 0; i < 32; ++i) {
            int l = i ^ j;
            if (l > i) {
                u64 a = st[i * 64 + lane];
                u64 b = st[l * 64 + lane];
                if (a > b) {
                    st[i * 64 + lane] = b;
                    st[l * 64 + lane] = a;
                }
            }
        }
    rk = st[31 * 64 + lane];
    cnt = 0;
}

__global__ __launch_bounds__(64)
void knn_kernel(const float* __restrict__ pts,
                const float* __restrict__ anchors,
                unsigned short* __restrict__ knn_out)
{
    const int blk  = blockIdx.x;       // 8bt * 3di * 32 sblk
    const int bt   = blk / 96;
    const int r    = blk % 96;
    const int di   = r / 32;
    const int sblk = r % 32;
    const int b = bt >> 2, t0 = bt & 3;
    int lnb = t0 + di - 1; lnb = lnb < 0 ? 0 : (lnb > 3 ? 3 : lnb);
    const float* nb = pts + (size_t)(b * 4 + lnb) * NPTS * 6;
    const int lane = threadIdx.x;
    const int s    = sblk * 64 + lane;

    const float* ap = anchors + ((size_t)bt * NS + s) * 3;
    float ax = ap[0], ay = ap[1], az = ap[2];

    __shared__ u64 st[65 * 64];        // 33.25 KB
    __shared__ float4 tile[512];       // 8 KB

    for (int e = 0; e < 64; ++e) st[e * 64 + lane] = ~0ull;
    u64 rk = ~0ull;
    int cnt = 0;

    for (int tb = 0; tb < NPTS; tb += 512) {
        __syncthreads();
#pragma unroll
        for (int q = 0; q < 8; ++q) {
            int c = q * 64 + lane;
            int n = tb + c;
            tile[c] = make_float4(nb[n*6+0], nb[n*6+1], nb[n*6+2], 0.0f);
        }
        __syncthreads();
        for (int c0 = 0; c0 < 512; c0 += 8) {
#pragma unroll
            for (int j = 0; j < 8; ++j) {
                float4 qv = tile[c0 + j];
                float dx = __fsub_rn(ax, qv.x);
                float dy = __fsub_rn(ay, qv.y);
                float dz = __fsub_rn(az, qv.z);
                float d2 = __fadd_rn(__fadd_rn(__fmul_rn(dx,dx), __fmul_rn(dy,dy)),
                                     __fmul_rn(dz,dz));
                u64 key = ((u64)__float_as_uint(d2) << 32)
                        | (unsigned)(tb + c0 + j);
                bool p = key < rk;
                int row = p ? (32 + cnt) : 64;
                st[row * 64 + lane] = key;
                cnt += p ? 1 : 0;
            }
            if (__any(cnt >= 24)) knn_compact(st, lane, cnt, rk);
        }
    }
    knn_compact(st, lane, cnt, rk);

    unsigned short* op = knn_out + (((size_t)bt * 3 + di) * NS + s) * KNNK;
#pragma unroll
    for (int e = 0; e < 32; ++e)
        op[e] = (unsigned short)(st[e * 64 + lane] & 0xFFFFull);
}

// ============================ MLP =============================
// (unchanged from R5 — register-tiled phase 2, ~350 us)
__global__ __launch_bounds__(256)
void mlp_kernel(const float* __restrict__ pts,
                const float* __restrict__ anchors,
                const unsigned short* __restrict__ knn,
                const float* __restrict__ Wd,
                const float* __restrict__ Wm,
                float* __restrict__ out_feats)
{
    const int blk   = blockIdx.x;
    const int bt    = blk >> 10;
    const int spair = blk & 1023;
    const int b = bt >> 2, t0 = bt & 3;
    const int tid = threadIdx.x;
    const int a   = tid >> 7;
    const int r   = tid & 127;
    const int pt  = r & 31;
    const int kt  = r >> 5;
    const int p   = r;
    const int s   = spair * 2 + a;
    const int p0  = pt * 4, k0 = kt * 8;

    __shared__ float WmT[64 * 128];
    __shared__ float Wds[256];
    __shared__ float h1[2][64][32];
    __shared__ float d4s[2][32][4];
    __shared__ float pmax[2][4][128];

    for (int i = tid; i < 8192; i += 256) {
        int pp = i >> 6, oo = i & 63;
        WmT[oo * 128 + pp] = Wm[i];
    }
    Wds[tid & 255] = Wd[tid & 255];

    float fsum = 0.0f;

    for (int dd = 0; dd < 3; ++dd) {
        __syncthreads();
        if (tid < 64) {
            int sa = tid >> 5, k = tid & 31;
            int ss = spair * 2 + sa;
            int lnb = t0 + dd - 1; lnb = lnb < 0 ? 0 : (lnb > 3 ? 3 : lnb);
            const float* nbf = pts + (size_t)(b*4 + lnb) * NPTS * 6;
            const float* ap = anchors + ((size_t)bt * NS + ss) * 3;
            int idx = knn[(((size_t)bt*3 + dd) * NS + ss) * KNNK + k];
            d4s[sa][k][0] = nbf[idx*6+0] - ap[0];
            d4s[sa][k][1] = nbf[idx*6+1] - ap[1];
            d4s[sa][k][2] = nbf[idx*6+2] - ap[2];
            d4s[sa][k][3] = (float)(dd - 1);
        }
        __syncthreads();
        {
            int k  = tid & 31;
            int oq = (tid >> 5) & 3;
            float4 dv = *(const float4*)&d4s[a][k][0];
#pragma unroll
            for (int ii = 0; ii < 16; ++ii) {
                int o = oq * 16 + ii;
                float4 w = *(const float4*)&Wds[o * 4];
                float h = fmaf(dv.x, w.x, fmaf(dv.y, w.y, fmaf(dv.z, w.z, dv.w * w.w)));
                h1[a][o][k] = fmaxf(h, 0.0f);
            }
        }
        __syncthreads();
        float acc[4][8];
#pragma unroll
        for (int i = 0; i < 4; ++i)
#pragma unroll
            for (int j = 0; j < 8; ++j) acc[i][j] = 0.0f;
        for (int o = 0; o < 64; ++o) {
            float4 wv = *(const float4*)&WmT[o * 128 + p0];
            float4 h0 = *(const float4*)&h1[a][o][k0];
            float4 h4 = *(const float4*)&h1[a][o][k0 + 4];
#pragma unroll
            for (int i = 0; i < 4; ++i) {
                float w = (i == 0) ? wv.x : (i == 1) ? wv.y : (i == 2) ? wv.z : wv.w;
                acc[i][0] = fmaf(w, h0.x, acc[i][0]);
                acc[i][1] = fmaf(w, h0.y, acc[i][1]);
                acc[i][2] = fmaf(w, h0.z, acc[i][2]);
                acc[i][3] = fmaf(w, h0.w, acc[i][3]);
                acc[i][4] = fmaf(w, h4.x, acc[i][4]);
                acc[i][5] = fmaf(w, h4.y, acc[i][5]);
                acc[i][6] = fmaf(w, h4.z, acc[i][6]);
                acc[i][7] = fmaf(w, h4.w, acc[i][7]);
            }
        }
        float4 pm;
#pragma unroll
        for (int i = 0; i < 4; ++i) {
            float m = acc[i][0];
#pragma unroll
            for (int j = 1; j < 8; ++j) m = fmaxf(m, acc[i][j]);
            ((float*)&pm)[i] = m;
        }
        *(float4*)&pmax[a][kt][p0] = pm;
        __syncthreads();
        float m = fmaxf(fmaxf(pmax[a][0][p], pmax[a][1][p]),
                        fmaxf(pmax[a][2][p], pmax[a][3][p]));
        fsum += fmaxf(m, 0.0f);
    }
    out_feats[((size_t)bt * 128 + p) * NS + s] = fsum;
}

// ========================== launcher ==========================
extern "C" void kernel_launch(void* const* d_in, const int* in_sizes, int n_in,
                              void* d_out, int out_size, void* d_ws, size_t ws_size,
                              hipStream_t stream)
{
    const float* pts = (const float*)d_in[0];   // [2,4,8192,6]
    const float* Wd  = (const float*)d_in[1];   // [64,4]
    const float* Wm  = (const float*)d_in[2];   // [128,64]

    float* out_xyz   = (float*)d_out;                 // [2,4,2048,3] == anchors
    float* out_feats = out_xyz + 8 * NS * 3;          // [2,4,128,2048]

    unsigned short* knn = (unsigned short*)d_ws;      // 8*3*2048*32 u16

    fps_kernel<<<8, 512, 0, stream>>>(pts, out_xyz);
    knn_kernel<<<8 * 3 * 32, 64, 0, stream>>>(pts, out_xyz, knn);
    mlp_kernel<<<8 * (NS / 2), 256, 0, stream>>>(pts, out_xyz, knn, Wd, Wm, out_feats);
}